// Round 5
// baseline (104.819 us; speedup 1.0000x reference)
//
#include <hip/hip_runtime.h>

#define N_PARTS 62
#define M_SAMP  512
#define D_DIM   256
#define MARGIN  0.2f
#define ROWS    (N_PARTS * M_SAMP)   // 31744
#define PART_ELEMS (M_SAMP * D_DIM)  // 131072 bf16 per part (packed layout, same size)

typedef unsigned short ushort_t;
typedef __attribute__((ext_vector_type(8))) short bf16x8;   // 8 bf16 = 4 VGPRs
typedef __attribute__((ext_vector_type(4))) float f32x4;

__device__ __forceinline__ ushort_t bf16_rne(float f) {
    unsigned u = __float_as_uint(f);
    unsigned r = u + 0x7fffu + ((u >> 16) & 1u);
    return (ushort_t)(r >> 16);
}

// async global->LDS, 16B per lane; LDS dest = wave-uniform base + lane*16
__device__ __forceinline__ void async_copy16(const ushort_t* g, ushort_t* l) {
    __builtin_amdgcn_global_load_lds(
        (const __attribute__((address_space(1))) unsigned int*)g,
        (__attribute__((address_space(3))) unsigned int*)l,
        16, 0, 0);
}

// K1: fp32 -> bf16 (RNE) + per-row sum-of-squares of the ROUNDED values +
// zero-init d_out. Output layout is CHUNK-MAJOR PACKED with the LDS bank
// swizzle baked in:
//   Fb[part][c=k>>5][row][ (q ^ ((row>>1)&3))*8 + (k&7) ],  q=(k>>3)&3
// so each per-chunk staging tile is one contiguous region and fused's
// global_load_lds runs at lane-contiguous (m97-style) addresses.
__global__ __launch_bounds__(256) void prep_kernel(const float* __restrict__ feat,
                                                   ushort_t* __restrict__ Fb,
                                                   float* __restrict__ sq,
                                                   float* __restrict__ out) {
    const int gid  = blockIdx.x * 256 + threadIdx.x;
    const int lane = threadIdx.x & 63;
    const int row  = gid >> 6;                    // one wave per row, exact grid
    const int part = row >> 9, rp = row & 511;
    const float4 v = ((const float4*)(feat + (size_t)row * D_DIM))[lane];
    ushort4 us;
    us.x = bf16_rne(v.x); us.y = bf16_rne(v.y);
    us.z = bf16_rne(v.z); us.w = bf16_rne(v.w);
    const float fx = __uint_as_float((unsigned)us.x << 16);
    const float fy = __uint_as_float((unsigned)us.y << 16);
    const float fz = __uint_as_float((unsigned)us.z << 16);
    const float fw = __uint_as_float((unsigned)us.w << 16);
    // lane covers k = lane*4 .. lane*4+3 : chunk c = lane>>3, quad q = (lane>>1)&3,
    // j = (lane&1)*4; physical slot s = q ^ ((rp>>1)&3).
    const int c = lane >> 3;
    const int q = (lane >> 1) & 3;
    const int j = (lane & 1) * 4;
    const int s = q ^ ((rp >> 1) & 3);
    *(ushort4*)(Fb + (size_t)part * PART_ELEMS + ((c * M_SAMP + rp) * 32) + s * 8 + j) = us;
    float ssum = fx * fx + fy * fy + fz * fz + fw * fw;
    #pragma unroll
    for (int off = 32; off > 0; off >>= 1) ssum += __shfl_xor(ssum, off);
    if (lane == 0) sq[row] = ssum;
    if (gid < 2 * N_PARTS) out[gid] = 0.0f;
}

// K2: fused Gram + triplet stats. Block = 64 rows x ALL 512 cols, grid 62x8.
// Packed layout makes every global_load_lds a contiguous 1 KB copy
// (addr = base + lane*16); per-chunk A tile = 4 KB contig, B tile = 8 KB contig.
// Double buffer via statically distinct LDS arrays, one barrier per chunk.
__global__ __launch_bounds__(256) void fused_triplet_kernel(const ushort_t* __restrict__ Fb,
                                                            const float* __restrict__ sq,
                                                            float* __restrict__ out) {
    const int n  = blockIdx.x;
    const int r0 = blockIdx.y * 64;
    const int tid = threadIdx.x;
    const int wave = tid >> 6, lane = tid & 63;
    const int wy = wave >> 1, wx = wave & 1;
    const ushort_t* F = Fb + (size_t)n * PART_ELEMS;
    const float* SQ = sq + n * M_SAMP;

    __shared__ ushort_t a0[64 * 32],  a1[64 * 32];    // A: 64 block rows x 32 k
    __shared__ ushort_t b0[128 * 32], b1[128 * 32];   // B: 128 cols x 32 k
    __shared__ float mrg[2][64][3];

    f32x4 acc[2][4] = {};
    float hp_r[2][4], hn_r[2][4], ds_r[2][4];
    #pragma unroll
    for (int mi = 0; mi < 2; ++mi)
        #pragma unroll
        for (int p = 0; p < 4; ++p) { hp_r[mi][p] = 0.f; hn_r[mi][p] = 1e30f; ds_r[mi][p] = 0.f; }

    float sqr[2][4];
    #pragma unroll
    for (int mi = 0; mi < 2; ++mi)
        #pragma unroll
        for (int p = 0; p < 4; ++p)
            sqr[mi][p] = SQ[r0 + wy * 32 + mi * 16 + (lane >> 4) * 4 + p];

    // contiguous staging: chunk c covers kchunk=c&7, col-tile cb=(c>>3)*128
    auto stage = [&](int c, ushort_t* la, ushort_t* lb) {
        const int kchunk = c & 7;
        const int cb = (c >> 3) * 128;
        const ushort_t* Ab = F + ((size_t)kchunk * M_SAMP + r0) * 32;   // 4 KB contig
        const ushort_t* Bb = F + ((size_t)kchunk * M_SAMP + cb) * 32;   // 8 KB contig
        async_copy16(Ab + (wave * 16) * 32 + lane * 8, la + (wave * 16) * 32);
        #pragma unroll
        for (int j = 0; j < 2; ++j)
            async_copy16(Bb + (wave * 32 + j * 16) * 32 + lane * 8,
                         lb + (wave * 32 + j * 16) * 32);
    };

    auto compute = [&](const ushort_t* la, const ushort_t* lb) {
        bf16x8 af[2], bf[4];
        #pragma unroll
        for (int mi = 0; mi < 2; ++mi) {
            const int ra = wy * 32 + mi * 16 + (lane & 15);
            const int sa = (lane >> 4) ^ ((ra >> 1) & 3);
            af[mi] = *(const bf16x8*)((const char*)la + ra * 64 + sa * 16);
        }
        #pragma unroll
        for (int ni = 0; ni < 4; ++ni) {
            const int rb = wx * 64 + ni * 16 + (lane & 15);
            const int sb = (lane >> 4) ^ ((rb >> 1) & 3);
            bf[ni] = *(const bf16x8*)((const char*)lb + rb * 64 + sb * 16);
        }
        #pragma unroll
        for (int mi = 0; mi < 2; ++mi)
            #pragma unroll
            for (int ni = 0; ni < 4; ++ni)
                acc[mi][ni] = __builtin_amdgcn_mfma_f32_16x16x32_bf16(
                    af[mi], bf[ni], acc[mi][ni], 0, 0, 0);
    };

    auto fold = [&](int ct) {
        float sqc[4];
        #pragma unroll
        for (int ni = 0; ni < 4; ++ni)
            sqc[ni] = SQ[ct * 128 + wx * 64 + ni * 16 + (lane & 15)];
        #pragma unroll
        for (int mi = 0; mi < 2; ++mi) {
            #pragma unroll
            for (int p = 0; p < 4; ++p) {
                const int Rg = (r0 + wy * 32 + mi * 16 + (lane >> 4) * 4 + p) >> 3;
                const float sr = sqr[mi][p];
                float ds = ds_r[mi][p], hp = hp_r[mi][p], hn = hn_r[mi][p];
                #pragma unroll
                for (int ni = 0; ni < 4; ++ni) {
                    const int C = ct * 128 + wx * 64 + ni * 16 + (lane & 15);
                    const float d2 = sr + sqc[ni] - 2.f * acc[mi][ni][p];
                    const float d  = sqrtf(fmaxf(d2, 0.f));
                    ds += d;
                    if (Rg == (C >> 3)) hp = fmaxf(hp, d);   // label = m>>3
                    else                hn = fminf(hn, d);
                }
                ds_r[mi][p] = ds; hp_r[mi][p] = hp; hn_r[mi][p] = hn;
            }
        }
        #pragma unroll
        for (int mi = 0; mi < 2; ++mi)
            #pragma unroll
            for (int ni = 0; ni < 4; ++ni)
                acc[mi][ni] = (f32x4){0.f, 0.f, 0.f, 0.f};
    };

    stage(0, a0, b0);
    for (int cc = 0; cc < 32; cc += 2) {   // pairs never straddle a col-tile
        __syncthreads();                   // publishes (a0,b0)[cc]; guards (a1,b1)
        stage(cc + 1, a1, b1);
        compute(a0, b0);
        __syncthreads();                   // publishes (a1,b1)[cc+1]; guards (a0,b0)
        if (cc + 2 < 32) stage(cc + 2, a0, b0);
        compute(a1, b1);
        if (((cc + 1) & 7) == 7) fold((cc + 1) >> 3);
    }

    // 16-lane column-group reduction (once per block)
    #pragma unroll
    for (int off = 1; off < 16; off <<= 1) {
        #pragma unroll
        for (int mi = 0; mi < 2; ++mi)
            #pragma unroll
            for (int p = 0; p < 4; ++p) {
                ds_r[mi][p] += __shfl_xor(ds_r[mi][p], off);
                hp_r[mi][p]  = fmaxf(hp_r[mi][p], __shfl_xor(hp_r[mi][p], off));
                hn_r[mi][p]  = fminf(hn_r[mi][p], __shfl_xor(hn_r[mi][p], off));
            }
    }
    if ((lane & 15) == 0) {
        const int q = lane >> 4;
        #pragma unroll
        for (int mi = 0; mi < 2; ++mi)
            #pragma unroll
            for (int p = 0; p < 4; ++p) {
                const int rl = wy * 32 + mi * 16 + q * 4 + p;
                mrg[wx][rl][0] = hp_r[mi][p];
                mrg[wx][rl][1] = hn_r[mi][p];
                mrg[wx][rl][2] = ds_r[mi][p];
            }
    }
    __syncthreads();
    if (tid < 64) {   // wave 0: one lane per row, merge col-halves + final sum
        const float hp = fmaxf(mrg[0][tid][0], mrg[1][tid][0]);
        const float hn = fminf(mrg[0][tid][1], mrg[1][tid][1]);
        float bd = mrg[0][tid][2] + mrg[1][tid][2];
        float bl = fmaxf(MARGIN + hp - hn, 0.f);
        #pragma unroll
        for (int off = 32; off > 0; off >>= 1) {
            bl += __shfl_xor(bl, off);
            bd += __shfl_xor(bd, off);
        }
        if (lane == 0) {
            atomicAdd(&out[n],           bl * (1.0f / 512.0f));
            atomicAdd(&out[N_PARTS + n], bd * (1.0f / (512.0f * 512.0f)));
        }
    }
}

extern "C" void kernel_launch(void* const* d_in, const int* in_sizes, int n_in,
                              void* d_out, int out_size, void* d_ws, size_t ws_size,
                              hipStream_t stream) {
    const float* feat = (const float*)d_in[0];    // [62, 512, 256] fp32
    float* out = (float*)d_out;                   // [124]

    ushort_t* Fb = (ushort_t*)d_ws;                                   // packed bf16
    float* sq    = (float*)((char*)d_ws + (size_t)ROWS * D_DIM * 2);  // row sum-of-squares

    prep_kernel<<<dim3(ROWS / 4), 256, 0, stream>>>(feat, Fb, sq, out);
    fused_triplet_kernel<<<dim3(N_PARTS, 8), 256, 0, stream>>>(Fb, sq, out);
}